// Round 2
// baseline (85.053 us; speedup 1.0000x reference)
//
#include <hip/hip_runtime.h>

#define NB 4096
#define TPB 256
#define NSPLIT 64
#define CHUNK (NB / NSPLIT)       // 64
#define KBLOCKS (NB / TPB)        // 16
#define PART_OFF 1024             // byte offset of partials in ws; counters in [0,64)

// Fused partial + last-block reduce.
// Grid (KBLOCKS, NSPLIT). Block (kb,s): bodies k in [kb*256, kb*256+256),
// sources i in [s*64, s*64+64). i is wave-uniform -> scalar loads.
__global__ __launch_bounds__(TPB) void nbody_fused(
    const float* __restrict__ x, const float* __restrict__ m,
    unsigned int* __restrict__ cnt, float2* __restrict__ part,
    float4* __restrict__ out)
{
    const int tid = threadIdx.x;
    const int kb  = blockIdx.x;
    const int s   = blockIdx.y;
    const int k   = kb * TPB + tid;
    const int i0  = s * CHUNK;

    const float4 xk = ((const float4*)x)[k];
    const float qx = xk.x, qy = xk.y;
    float ax = 0.f, ay = 0.f;

    // This block's chunk lies inside this kb's body range -> may hit i==k.
    const bool diagBlock = ((i0 >> 8) == kb);

    if (diagBlock) {
        #pragma unroll 8
        for (int ii = 0; ii < CHUNK; ++ii) {
            const int i = i0 + ii;                    // wave-uniform
            const float4 xi = ((const float4*)x)[i];  // -> s_load_dwordx4
            const float mi = m[i];
            const float dx = qx - xi.x;
            const float dy = qy - xi.y;
            float sq = fmaf(dx, dx, dy * dy);
            const bool self = (i == k);
            sq = self ? 1.0f : sq;                    // keep rsqrt finite
            const float rinv = rsqrtf(sq);
            float w = rinv * rinv * rinv * mi;
            w = self ? 0.f : w;                       // self-pair has zero q-grad
            ax = fmaf(dx, w, ax);
            ay = fmaf(dy, w, ay);
        }
    } else {
        #pragma unroll 8
        for (int ii = 0; ii < CHUNK; ++ii) {
            const int i = i0 + ii;
            const float4 xi = ((const float4*)x)[i];
            const float mi = m[i];
            const float dx = qx - xi.x;
            const float dy = qy - xi.y;
            const float sq = fmaf(dx, dx, dy * dy);
            const float rinv = rsqrtf(sq);
            const float w = rinv * rinv * rinv * mi;
            ax = fmaf(dx, w, ax);
            ay = fmaf(dy, w, ay);
        }
    }

    // Adjacent pairs |k-i|==1 have weight 2 under tril(.,diagonal=1): the main
    // loop counted them once; the split-chunk that OWNS the neighbor index
    // adds the extra unit. Exactly one block per (k, neighbor) qualifies.
    #pragma unroll
    for (int d = -1; d <= 1; d += 2) {
        const int nbi = k + d;
        if (nbi >= i0 && nbi < i0 + CHUNK) {          // implies 0 <= nbi < NB
            const float4 xi = ((const float4*)x)[nbi];
            const float dx = qx - xi.x;
            const float dy = qy - xi.y;
            const float sq = fmaf(dx, dx, dy * dy);
            const float rinv = rsqrtf(sq);
            const float w = rinv * rinv * rinv * m[nbi];
            ax = fmaf(dx, w, ax);
            ay = fmaf(dy, w, ay);
        }
    }

    const float mk = m[k];
    part[s * NB + k] = make_float2(ax * mk, ay * mk);

    // Last-block-per-kb reduction (threadFenceReduction pattern).
    __threadfence();
    __syncthreads();
    __shared__ int last;
    if (tid == 0)
        last = (atomicAdd(&cnt[kb], 1u) == (unsigned)(NSPLIT - 1));
    __syncthreads();

    if (last) {
        __threadfence();                              // acquire side
        float sx = 0.f, sy = 0.f;
        #pragma unroll 8
        for (int ss = 0; ss < NSPLIT; ++ss) {
            const float2 v = part[ss * NB + k];
            sx += v.x;
            sy += v.y;
        }
        const float m0inv = 1.0f / m[0];
        out[k] = make_float4(xk.z * m0inv, xk.w * m0inv, sx, sy);
    }
}

// Fallback if workspace is too small: single-pass, correct but slow.
__global__ __launch_bounds__(TPB) void nbody_full(
    const float* __restrict__ x, const float* __restrict__ m,
    float* __restrict__ out)
{
    const int tid = threadIdx.x;
    const int k   = blockIdx.x * TPB + tid;

    const float4 xk = ((const float4*)x)[k];
    const float qx = xk.x, qy = xk.y;
    float ax = 0.f, ay = 0.f;

    for (int i = 0; i < NB; ++i) {
        const float4 xi = ((const float4*)x)[i];
        const float dx = qx - xi.x;
        const float dy = qy - xi.y;
        float sq = fmaf(dx, dx, dy * dy);
        const int dlt = k - i;
        sq = (dlt == 0) ? 1.0f : sq;
        const float rinv = rsqrtf(sq);
        float w = rinv * rinv * rinv * m[i];
        const float c = (dlt == 0) ? 0.f : ((dlt == 1 || dlt == -1) ? 2.f : 1.f);
        w *= c;
        ax = fmaf(dx, w, ax);
        ay = fmaf(dy, w, ay);
    }
    const float mk = m[k];
    const float m0inv = 1.0f / m[0];
    ((float4*)out)[k] = make_float4(xk.z * m0inv, xk.w * m0inv, ax * mk, ay * mk);
}

extern "C" void kernel_launch(void* const* d_in, const int* in_sizes, int n_in,
                              void* d_out, int out_size, void* d_ws, size_t ws_size,
                              hipStream_t stream) {
    const float* x = (const float*)d_in[0];
    const float* m = (const float*)d_in[1];

    const size_t needed = PART_OFF + (size_t)NSPLIT * NB * sizeof(float2);
    if (ws_size >= needed) {
        hipMemsetAsync(d_ws, 0, 64, stream);          // zero the 16 kb-counters
        dim3 grid(KBLOCKS, NSPLIT);
        nbody_fused<<<grid, dim3(TPB), 0, stream>>>(
            x, m, (unsigned int*)d_ws,
            (float2*)((char*)d_ws + PART_OFF), (float4*)d_out);
    } else {
        nbody_full<<<dim3(KBLOCKS), dim3(TPB), 0, stream>>>(x, m, (float*)d_out);
    }
}

// Round 3
// 12.403 us; speedup vs baseline: 6.8577x; 6.8577x over previous
//
#include <hip/hip_runtime.h>

#define NB 4096
#define TPB 1024
#define WPB (TPB / 64)        // 16 waves (bodies) per block
#define NBLK (NB / WPB)       // 256 blocks -> 1 per CU
#define NT (NB / 64)          // 64 source iterations per lane

// One wave per body k. Lane l accumulates sources i = 64t + l, t in [0,64).
// All 4096 sources staged once in LDS (48 KB). Intra-wave shfl_xor reduction.
// No workspace, no atomics, no fences -> deterministic, single kernel.
__global__ __launch_bounds__(TPB) void nbody_wave(
    const float* __restrict__ x, const float* __restrict__ m,
    float4* __restrict__ out)
{
    __shared__ float2 q2[NB];     // 32 KB: (qx, qy)
    __shared__ float  ms[NB];     // 16 KB: mass

    const int tid = threadIdx.x;

    // Stage all sources: 4 coalesced float4 + 4 float loads per thread.
    #pragma unroll
    for (int t = 0; t < NB / TPB; ++t) {
        const int i = t * TPB + tid;
        const float4 xi = ((const float4*)x)[i];
        q2[i] = make_float2(xi.x, xi.y);
        ms[i] = m[i];
    }
    __syncthreads();

    const int wave = tid >> 6;
    const int lane = tid & 63;
    const int k = blockIdx.x * WPB + wave;

    const float2 qk = q2[k];      // LDS broadcast (wave-uniform)
    const float qx = qk.x, qy = qk.y;
    float ax = 0.f, ay = 0.f;

    // Self-pair (i==k): dx=dy=0 and sq clamps to 1e-12 -> w finite, dx*w == 0.
    // No compares/selects needed in the hot loop.
    #pragma unroll 8
    for (int t = 0; t < NT; ++t) {
        const int i = t * 64 + lane;
        const float2 qi = q2[i];
        const float mi = ms[i];
        const float dx = qx - qi.x;
        const float dy = qy - qi.y;
        float sq = fmaf(dx, dx, dy * dy);
        sq = fmaxf(sq, 1e-12f);
        const float rinv = rsqrtf(sq);
        const float w = rinv * rinv * rinv * mi;
        ax = fmaf(dx, w, ax);
        ay = fmaf(dy, w, ay);
    }

    // Adjacent pairs |k-i|==1 carry weight 2 under tril(.,diagonal=1); the main
    // loop counted them once. Lanes 0/1 add the extra unit weight.
    int nbi = -2;
    if (lane == 0) nbi = k - 1;
    else if (lane == 1) nbi = k + 1;
    if (nbi >= 0 && nbi < NB) {
        const float2 qi = q2[nbi];
        const float dx = qx - qi.x;
        const float dy = qy - qi.y;
        const float sq = fmaf(dx, dx, dy * dy);
        const float rinv = rsqrtf(sq);
        const float w = rinv * rinv * rinv * ms[nbi];
        ax = fmaf(dx, w, ax);
        ay = fmaf(dy, w, ay);
    }

    // Wave butterfly reduction (fixed order -> bitwise deterministic).
    #pragma unroll
    for (int off = 32; off > 0; off >>= 1) {
        ax += __shfl_xor(ax, off);
        ay += __shfl_xor(ay, off);
    }

    if (lane == 0) {
        const float4 xk = ((const float4*)x)[k];
        const float mk = m[k];
        const float m0inv = 1.0f / m[0];
        out[k] = make_float4(xk.z * m0inv, xk.w * m0inv, ax * mk, ay * mk);
    }
}

extern "C" void kernel_launch(void* const* d_in, const int* in_sizes, int n_in,
                              void* d_out, int out_size, void* d_ws, size_t ws_size,
                              hipStream_t stream) {
    const float* x = (const float*)d_in[0];
    const float* m = (const float*)d_in[1];
    nbody_wave<<<dim3(NBLK), dim3(TPB), 0, stream>>>(x, m, (float4*)d_out);
}